// Round 16
// baseline (277.752 us; speedup 1.0000x reference)
//
#include <hip/hip_runtime.h>

#define EMBED 768
#define NHEAD 12
#define HDIM 64
#define BATCH 8
#define SEQ 1024
#define ROWS (BATCH*SEQ)      // 8192
#define QKVN (3*EMBED)        // 2304
#define ATTN_SCALE 0.125f     // 1/sqrt(64)

typedef short s16x8 __attribute__((ext_vector_type(8)));
typedef short s16x4 __attribute__((ext_vector_type(4)));
typedef float f32x4 __attribute__((ext_vector_type(4)));

__device__ __forceinline__ float bf2f(unsigned short u) {
    union { unsigned int i; float f; } v; v.i = ((unsigned int)u) << 16; return v.f;
}
__device__ __forceinline__ unsigned short f2bf(float f) {
    unsigned int i = __builtin_bit_cast(unsigned int, f);
    i += 0x7FFFu + ((i >> 16) & 1u);   // RNE; finite values only
    return (unsigned short)(i >> 16);
}

// async global->LDS, 16 bytes per lane; LDS dest = wave-uniform base + lane*16
__device__ __forceinline__ void async16(short* lds, const unsigned short* g) {
    __builtin_amdgcn_global_load_lds(
        (const __attribute__((address_space(1))) unsigned int*)g,
        (__attribute__((address_space(3))) unsigned int*)lds,
        16, 0, 0);
}

__device__ __forceinline__ f32x4 mfma16(s16x4 a, s16x4 b, f32x4 c) {
#if __has_builtin(__builtin_amdgcn_mfma_f32_16x16x16bf16_1k)
    return __builtin_amdgcn_mfma_f32_16x16x16bf16_1k(a, b, c, 0, 0, 0);
#else
    asm volatile("v_mfma_f32_16x16x16_bf16 %0, %1, %2, %0" : "+v"(c) : "v"(a), "v"(b));
    return c;
#endif
}

// Fused prep (round-14 proven: conversion in prep beats in-GEMM fusion, r15).
// blk [0,432):   qkv_w fp32[768][2304] -> bf16 [2304][768]  (64x64 LDS tile transpose)
// blk [432,576): proj_w fp32[768][768] -> bf16 [768][768]
// blk [576,3648): hidden fp32 -> bf16 row-convert (8 elem/thread)
__global__ __launch_bounds__(256) void prep_k(
    const float* __restrict__ qkv_w, unsigned short* __restrict__ WqkvT,
    const float* __restrict__ proj_w, unsigned short* __restrict__ WprojT,
    const float* __restrict__ hidden, unsigned short* __restrict__ hiddenBf)
{
    __shared__ float tile[64][65];
    int blk = blockIdx.x;
    int t = threadIdx.x;
    if (blk < 576) {
        const float* in; unsigned short* outp; int K, N, tx, ty;
        if (blk < 432) { in = qkv_w; outp = WqkvT; K = EMBED; N = QKVN; tx = blk % 36; ty = blk / 36; }
        else { int b2 = blk - 432; in = proj_w; outp = WprojT; K = EMBED; N = EMBED; tx = b2 % 12; ty = b2 / 12; }
        int n0 = tx * 64, k0 = ty * 64;
        int c = t & 63, r0 = t >> 6;
        #pragma unroll
        for (int i = 0; i < 16; i++) {
            int r = r0 * 16 + i;
            tile[r][c] = in[(long long)(k0 + r) * N + n0 + c];   // coalesced 256B/row-group
        }
        __syncthreads();
        #pragma unroll
        for (int i = 0; i < 16; i++) {
            int nr = r0 * 16 + i;
            outp[(long long)(n0 + nr) * K + k0 + c] = f2bf(tile[c][nr]); // coalesced writes
        }
    } else {
        int tid = (blk - 576) * 256 + t;
        int base = tid * 8;
        float4 f0 = *(const float4*)&hidden[base];
        float4 f1 = *(const float4*)&hidden[base + 4];
        s16x8 a;
        a[0] = (short)f2bf(f0.x); a[1] = (short)f2bf(f0.y);
        a[2] = (short)f2bf(f0.z); a[3] = (short)f2bf(f0.w);
        a[4] = (short)f2bf(f1.x); a[5] = (short)f2bf(f1.y);
        a[6] = (short)f2bf(f1.z); a[7] = (short)f2bf(f1.w);
        *(s16x8*)&hiddenBf[base] = a;
    }
}

// m97-class GEMM + 2-phase double-buffer (PROVEN round 9/10/14 template):
//   BN=128 (QKV): byte-identical to the round-9 proven path. 4 waves, wave 64x64.
//   BN=64  (proj): same sync/swizzle structure, wave 64x32 (acc[4][2]); B-tile
//     64x32 staged by 1 async16/wave; LDS 24KB. Fixes proj grid starvation:
//     grid 64x12 = 768 blocks = 3 blocks/CU (was 384 = 1.5/CU half-idle).
// Per K-step: stage(next->other buffer) BEFORE ds_read+MFMA(cur), ONE barrier.
// XCD slab swizzle (bijective for gridDim.x=64, any gridDim.y).
template <int OUT_F32, int BN>
__global__ __launch_bounds__(256) void gemm128(
    const unsigned short* __restrict__ A,
    const unsigned short* __restrict__ Bt,
    const float* __restrict__ bias,
    void* __restrict__ Cv,
    int M, int N, int K)
{
    constexpr int WN = (BN == 128) ? 64 : 32;   // wave output cols
    constexpr int NJ = WN / 16;                 // B fragments per wave
    __shared__ short As[2][128 * 32];
    __shared__ short Bs[2][BN * 32];
    int t = threadIdx.x, lane = t & 63, w = t >> 6;
    int quad = lane >> 4, low = lane & 15;
    // orig = (local<<3)|xcd ; (bx,by) = (xcd*8+(local&7), local>>3) — bijective.
    int orig = blockIdx.y * gridDim.x + blockIdx.x;
    int xcd = orig & 7;
    int local = orig >> 3;
    int bx = xcd * 8 + (local & 7);
    int by = local >> 3;
    int m0 = bx * 128, n0 = by * BN;
    int wm = (w & 1) * 64, wn = (w >> 1) * WN;

    // A staging (identical for both BN): chunks w*128+lane, +64
    int ci0 = w * 128 + lane;
    int r0 = ci0 >> 2, c0 = (ci0 & 3) ^ ((r0 >> 1) & 3);
    int ci1 = ci0 + 64;
    int r1 = ci1 >> 2, c1 = (ci1 & 3) ^ ((r1 >> 1) & 3);
    const unsigned short* pa0 = A + (long long)(m0 + r0) * K + c0 * 8;
    const unsigned short* pa1 = A + (long long)(m0 + r1) * K + c1 * 8;
    int alo0 = (w * 128) * 8;
    int alo1 = (w * 128 + 64) * 8;
    // B staging: BN=128 -> 2 chunks/thread (w*128+lane, +64); BN=64 -> 1 (w*64+lane)
    int cib0 = (BN == 128) ? (w * 128 + lane) : (w * 64 + lane);
    int rb0 = cib0 >> 2, cb0 = (cib0 & 3) ^ ((rb0 >> 1) & 3);
    const unsigned short* pb0 = Bt + (long long)(n0 + rb0) * K + cb0 * 8;
    int blo0 = (BN == 128) ? (w * 128) * 8 : (w * 64) * 8;
    int cib1 = cib0 + 64;
    int rb1 = cib1 >> 2, cb1 = (cib1 & 3) ^ ((rb1 >> 1) & 3);
    const unsigned short* pb1 = Bt + (long long)(n0 + rb1) * K + cb1 * 8;
    int blo1 = (w * 128 + 64) * 8;   // used only when BN==128

    // prologue: stage K-step 0 into buffer 0
    async16(&As[0][alo0], pa0);
    async16(&As[0][alo1], pa1);
    async16(&Bs[0][blo0], pb0);
    if (BN == 128) async16(&Bs[0][blo1], pb1);
    __syncthreads();

    f32x4 acc[4][NJ] = {};
    int cur = 0;
    for (int k0 = 0; k0 < K; k0 += 32) {
        int nxt = cur ^ 1;
        // stage next K-step into the other buffer (issued before compute;
        // lands by the barrier below, latency hidden under ds_read+MFMA)
        if (k0 + 32 < K) {
            async16(&As[nxt][alo0], pa0 + k0 + 32);
            async16(&As[nxt][alo1], pa1 + k0 + 32);
            async16(&Bs[nxt][blo0], pb0 + k0 + 32);
            if (BN == 128) async16(&Bs[nxt][blo1], pb1 + k0 + 32);
        }
        const short* as = As[cur];
        const short* bs = Bs[cur];
        s16x8 af[4], bfr[NJ];
        #pragma unroll
        for (int i = 0; i < 4; i++) {
            int ra = wm + i * 16 + low;
            af[i] = *(const s16x8*)&as[ra * 32 + ((quad ^ ((ra >> 1) & 3)) * 8)];
        }
        #pragma unroll
        for (int j = 0; j < NJ; j++) {
            int rbn = wn + j * 16 + low;
            bfr[j] = *(const s16x8*)&bs[rbn * 32 + ((quad ^ ((rbn >> 1) & 3)) * 8)];
        }
        #pragma unroll
        for (int i = 0; i < 4; i++)
            #pragma unroll
            for (int j = 0; j < NJ; j++)
                acc[i][j] = __builtin_amdgcn_mfma_f32_16x16x32_bf16(af[i], bfr[j], acc[i][j], 0, 0, 0);
        __syncthreads();   // reads of cur done (lgkm), stage of nxt landed (vmcnt)
        cur = nxt;
    }
    #pragma unroll
    for (int i = 0; i < 4; i++)
        #pragma unroll
        for (int j = 0; j < NJ; j++)
            #pragma unroll
            for (int r = 0; r < 4; r++) {
                int m = m0 + wm + i * 16 + quad * 4 + r;
                int n = n0 + wn + j * 16 + low;
                float v = acc[i][j][r] + bias[n];
                if (OUT_F32) ((float*)Cv)[(long long)m * N + n] = v;
                else ((unsigned short*)Cv)[(long long)m * N + n] = f2bf(v);
            }
}

// MFMA flash attention (round-10/14 PROVEN structure + symmetric epilogue):
// 2-gang KV split, 32 q-rows/wave, single-buffered staging, expf softmax,
// in-register P via swapped QK^T + v_cvt_pk_bf16_f32.
// NEW (r16): symmetric cross-gang combine — gang g outputs d-columns
// nt in {2g, 2g+1}; each gang dumps its o for the OTHER half + lsum, then
// adds the counterpart and writes its own half. Halves epilogue work/thread,
// doubles ctx-store parallelism. fp32 adds commute -> bit-identical output.
__global__ __launch_bounds__(512) void attn_k(
    const unsigned short* __restrict__ mixed,  // [8192][2304] : Q|K|V per row (bf16)
    unsigned short* __restrict__ ctx)          // [8192][768]
{
    // staging: per gang Ks 8192B + Vt 8704B = 16896B; 2 gangs 33792B.
    // epilogue overlay: xo 2 regions x 1024 f32x4 = 32768B + xl 1024 f32 = 4096B -> 36864B.
    __shared__ __align__(16) char smem[36864];
    int blk = blockIdx.x;
    int bh = blk % 96;                 // XCD-grouped: 96 == 0 (mod 8)
    int qc = blk / 96;
    int b = bh / NHEAD, h = bh - b * NHEAD;
    int t = threadIdx.x;
    int tl = t & 255;                  // intra-gang thread id
    int lane = t & 63, w = t >> 6;     // w in 0..7
    int wq = w & 3, gang = w >> 2;
    int quad = lane >> 4, low = lane & 15;
    long long rowbase = (long long)b * SEQ;
    int q0 = qc * 128 + wq * 32;
    int hoff = h * HDIM;

    short* Ks = (short*)(smem + gang * 16896);        // K tile [kv][d], chunk-XOR swizzled
    short* Vt = (short*)(smem + gang * 16896 + 8192); // V^T tile [d][kv], kv padded ->68

    // Q fragments (B-operand of swapped QK^T; layout identical to A-frag): [qh][dhalf]
    s16x8 qf[2][2];
    #pragma unroll
    for (int qh = 0; qh < 2; qh++) {
        long long r = (rowbase + q0 + qh * 16 + low) * QKVN + hoff;
        qf[qh][0] = *(const s16x8*)&mixed[r + quad * 8];
        qf[qh][1] = *(const s16x8*)&mixed[r + 32 + quad * 8];
    }

    // K staging (per gang): slot = wq*128 + lane (+64); row = slot>>3, chunk = slot&7.
    // LDS phys chunk c of row r holds global d-chunk (c ^ (r&7)); read applies same XOR.
    int s0 = wq * 128 + lane;
    int kr0 = s0 >> 3, kc0 = s0 & 7;
    int kg = kc0 ^ (kr0 & 7);          // (kr0+8)&7 == kr0&7, so same for both slots
    const unsigned short* pk0 = mixed + (rowbase + kr0) * QKVN + EMBED + hoff + kg * 8;
    const unsigned short* pk1 = mixed + (rowbase + kr0 + 8) * QKVN + EMBED + hoff + kg * 8;
    short* lk0 = Ks + (wq * 128) * 8;
    short* lk1 = Ks + (wq * 128 + 64) * 8;

    // V staging (per gang): thread owns d = dblk*4..+3, kv rows rq*4..+3
    int dblk = tl & 15, rq = tl >> 4;
    const unsigned short* pv = mixed + (rowbase + rq * 4) * QKVN + 2 * EMBED + hoff + dblk * 4;

    f32x4 o[2][4] = {};
    float lsum[2] = {0.f, 0.f};

    int kvbase = gang * 512;           // gang's KV half
    for (int it = 0; it < 8; it++) {
        long long koff = (long long)(kvbase + it * 64) * QKVN;
        __syncthreads();
        async16(lk0, pk0 + koff);
        async16(lk1, pk1 + koff);
        s16x4 v0 = *(const s16x4*)&pv[koff];
        s16x4 v1 = *(const s16x4*)&pv[koff + QKVN];
        s16x4 v2 = *(const s16x4*)&pv[koff + 2 * QKVN];
        s16x4 v3 = *(const s16x4*)&pv[koff + 3 * QKVN];
        #pragma unroll
        for (int k = 0; k < 4; k++) {
            s16x4 wv;
            wv[0] = v0[k]; wv[1] = v1[k]; wv[2] = v2[k]; wv[3] = v3[k];
            *(s16x4*)&Vt[(dblk * 4 + k) * 68 + rq * 4] = wv;
        }
        __syncthreads();

        // S^T: per kv-16 block n, sT[qh][n][r] = S[q0+qh*16+low][kv...]
        f32x4 sT[2][4] = {};
        __builtin_amdgcn_s_setprio(1);
        #pragma unroll
        for (int n = 0; n < 4; n++) {
            int rr = n * 16 + low;
            int key = low & 7;
            s16x8 kf0 = *(const s16x8*)&Ks[rr * 64 + ((quad ^ key) * 8)];
            s16x8 kf1 = *(const s16x8*)&Ks[rr * 64 + (((quad + 4) ^ key) * 8)];
            sT[0][n] = __builtin_amdgcn_mfma_f32_16x16x32_bf16(kf0, qf[0][0], sT[0][n], 0, 0, 0);
            sT[0][n] = __builtin_amdgcn_mfma_f32_16x16x32_bf16(kf1, qf[0][1], sT[0][n], 0, 0, 0);
            sT[1][n] = __builtin_amdgcn_mfma_f32_16x16x32_bf16(kf0, qf[1][0], sT[1][n], 0, 0, 0);
            sT[1][n] = __builtin_amdgcn_mfma_f32_16x16x32_bf16(kf1, qf[1][1], sT[1][n], 0, 0, 0);
        }
        __builtin_amdgcn_s_setprio(0);

        // P = exp(S*scale): in-register, pack straight into x16 A-fragments
        s16x4 pf[2][4];
        #pragma unroll
        for (int qh = 0; qh < 2; qh++)
            #pragma unroll
            for (int n = 0; n < 4; n++) {
                float e0 = __expf(sT[qh][n][0] * ATTN_SCALE);
                float e1 = __expf(sT[qh][n][1] * ATTN_SCALE);
                float e2 = __expf(sT[qh][n][2] * ATTN_SCALE);
                float e3 = __expf(sT[qh][n][3] * ATTN_SCALE);
                lsum[qh] += (e0 + e1) + (e2 + e3);
                unsigned int w0, w1;
                asm("v_cvt_pk_bf16_f32 %0, %1, %2" : "=v"(w0) : "v"(e0), "v"(e1));
                asm("v_cvt_pk_bf16_f32 %0, %1, %2" : "=v"(w1) : "v"(e2), "v"(e3));
                union { unsigned int u[2]; s16x4 v; } pu;
                pu.u[0] = w0; pu.u[1] = w1;
                pf[qh][n] = pu.v;
            }

        // O += P @ V  (x16 MFMAs; V frag = contiguous b64 from V^T)
        __builtin_amdgcn_s_setprio(1);
        #pragma unroll
        for (int nt = 0; nt < 4; nt++) {
            int drow = nt * 16 + low;
            #pragma unroll
            for (int n = 0; n < 4; n++) {
                s16x4 vf = *(const s16x4*)&Vt[drow * 68 + n * 16 + quad * 4];
                o[0][nt] = mfma16(pf[0][n], vf, o[0][nt]);
                o[1][nt] = mfma16(pf[1][n], vf, o[1][nt]);
            }
        }
        __builtin_amdgcn_s_setprio(0);
    }

    // full row-sums within gang: combine the 4 quad-partials for each q=low
    #pragma unroll
    for (int qh = 0; qh < 2; qh++) {
        lsum[qh] += __shfl_xor(lsum[qh], 16, 64);
        lsum[qh] += __shfl_xor(lsum[qh], 32, 64);
    }

    // symmetric cross-gang combine (no-max softmax => pure addition).
    // gang g outputs nt in {2g, 2g+1}; dumps its o for the OTHER half.
    f32x4* xo = (f32x4*)smem;                 // [gang][wq][qh][j][lane] = 2048 x f32x4
    float*  xl = (float*)(smem + 32768);      // [gang][wq][qh][lane]   = 1024 x f32
    int og = gang ^ 1;
    __syncthreads();                          // all staging reads done before overwrite
    #pragma unroll
    for (int qh = 0; qh < 2; qh++) {
        #pragma unroll
        for (int j = 0; j < 2; j++)
            xo[((((gang * 4 + wq) * 2 + qh) * 2 + j)) * 64 + lane] = o[qh][og * 2 + j];
        xl[((gang * 4 + wq) * 2 + qh) * 64 + lane] = lsum[qh];
    }
    __syncthreads();
    #pragma unroll
    for (int qh = 0; qh < 2; qh++) {
        float lt = lsum[qh] + xl[((og * 4 + wq) * 2 + qh) * 64 + lane];
        f32x4 oo[2];
        #pragma unroll
        for (int j = 0; j < 2; j++)
            oo[j] = o[qh][gang * 2 + j] + xo[((((og * 4 + wq) * 2 + qh) * 2 + j)) * 64 + lane];
        #pragma unroll
        for (int r = 0; r < 4; r++) {
            float inv = 1.0f / __shfl(lt, quad * 4 + r, 64);
            int q = q0 + qh * 16 + quad * 4 + r;
            #pragma unroll
            for (int j = 0; j < 2; j++) {
                int nt = gang * 2 + j;
                ctx[(rowbase + q) * EMBED + hoff + nt * 16 + low] =
                    f2bf(oo[j][r] * inv);
            }
        }
    }
}

extern "C" void kernel_launch(void* const* d_in, const int* in_sizes, int n_in,
                              void* d_out, int out_size, void* d_ws, size_t ws_size,
                              hipStream_t stream) {
    const float* hidden = (const float*)d_in[0];
    const float* qkv_w  = (const float*)d_in[1];
    const float* qkv_b  = (const float*)d_in[2];
    const float* proj_w = (const float*)d_in[3];
    const float* proj_b = (const float*)d_in[4];
    float* out = (float*)d_out;        // fp32 output

    char* ws = (char*)d_ws;
    // hiddenBf dead after QKV GEMM; ctx written only by attn -> alias (stream-serialized).
    unsigned short* hiddenBf = (unsigned short*)ws;                      // 8192x768  bf16
    unsigned short* ctx      = (unsigned short*)ws;                      // aliases hiddenBf
    unsigned short* WqkvT    = (unsigned short*)(ws + 12582912);         // 2304x768  bf16
    unsigned short* WprojT   = (unsigned short*)(ws + 16121856);         // 768x768   bf16
    unsigned short* mixed    = (unsigned short*)(ws + 17301504);         // 8192x2304 bf16

    prep_k<<<dim3(3648), 256, 0, stream>>>(qkv_w, WqkvT, proj_w, WprojT, hidden, hiddenBf);
    gemm128<0, 128><<<dim3(ROWS / 128, QKVN / 128), 256, 0, stream>>>(
        hiddenBf, WqkvT, qkv_b, mixed, ROWS, QKVN, EMBED);
    attn_k<<<dim3(96 * 8), 512, 0, stream>>>(mixed, ctx);
    gemm128<1, 64><<<dim3(ROWS / 128, EMBED / 64), 256, 0, stream>>>(
        ctx, WprojT, proj_b, out, ROWS, EMBED, EMBED);
}

// Round 17
// 187.752 us; speedup vs baseline: 1.4794x; 1.4794x over previous
//
#include <hip/hip_runtime.h>

#define EMBED 768
#define NHEAD 12
#define HDIM 64
#define BATCH 8
#define SEQ 1024
#define ROWS (BATCH*SEQ)      // 8192
#define QKVN (3*EMBED)        // 2304
#define ATTN_SCALE 0.125f     // 1/sqrt(64)

typedef short s16x8 __attribute__((ext_vector_type(8)));
typedef short s16x4 __attribute__((ext_vector_type(4)));
typedef float f32x4 __attribute__((ext_vector_type(4)));

__device__ __forceinline__ float bf2f(unsigned short u) {
    union { unsigned int i; float f; } v; v.i = ((unsigned int)u) << 16; return v.f;
}
__device__ __forceinline__ unsigned short f2bf(float f) {
    unsigned int i = __builtin_bit_cast(unsigned int, f);
    i += 0x7FFFu + ((i >> 16) & 1u);   // RNE; finite values only
    return (unsigned short)(i >> 16);
}

// async global->LDS, 16 bytes per lane; LDS dest = wave-uniform base + lane*16
__device__ __forceinline__ void async16(short* lds, const unsigned short* g) {
    __builtin_amdgcn_global_load_lds(
        (const __attribute__((address_space(1))) unsigned int*)g,
        (__attribute__((address_space(3))) unsigned int*)lds,
        16, 0, 0);
}

__device__ __forceinline__ f32x4 mfma16(s16x4 a, s16x4 b, f32x4 c) {
#if __has_builtin(__builtin_amdgcn_mfma_f32_16x16x16bf16_1k)
    return __builtin_amdgcn_mfma_f32_16x16x16bf16_1k(a, b, c, 0, 0, 0);
#else
    asm volatile("v_mfma_f32_16x16x16_bf16 %0, %1, %2, %0" : "+v"(c) : "v"(a), "v"(b));
    return c;
#endif
}

// Fused prep (round-14 proven: conversion in prep beats in-GEMM fusion, r15).
// blk [0,432):   qkv_w fp32[768][2304] -> bf16 [2304][768]  (64x64 LDS tile transpose)
// blk [432,576): proj_w fp32[768][768] -> bf16 [768][768]
// blk [576,3648): hidden fp32 -> bf16 row-convert (8 elem/thread)
__global__ __launch_bounds__(256) void prep_k(
    const float* __restrict__ qkv_w, unsigned short* __restrict__ WqkvT,
    const float* __restrict__ proj_w, unsigned short* __restrict__ WprojT,
    const float* __restrict__ hidden, unsigned short* __restrict__ hiddenBf)
{
    __shared__ float tile[64][65];
    int blk = blockIdx.x;
    int t = threadIdx.x;
    if (blk < 576) {
        const float* in; unsigned short* outp; int K, N, tx, ty;
        if (blk < 432) { in = qkv_w; outp = WqkvT; K = EMBED; N = QKVN; tx = blk % 36; ty = blk / 36; }
        else { int b2 = blk - 432; in = proj_w; outp = WprojT; K = EMBED; N = EMBED; tx = b2 % 12; ty = b2 / 12; }
        int n0 = tx * 64, k0 = ty * 64;
        int c = t & 63, r0 = t >> 6;
        #pragma unroll
        for (int i = 0; i < 16; i++) {
            int r = r0 * 16 + i;
            tile[r][c] = in[(long long)(k0 + r) * N + n0 + c];   // coalesced 256B/row-group
        }
        __syncthreads();
        #pragma unroll
        for (int i = 0; i < 16; i++) {
            int nr = r0 * 16 + i;
            outp[(long long)(n0 + nr) * K + k0 + c] = f2bf(tile[c][nr]); // coalesced writes
        }
    } else {
        int tid = (blk - 576) * 256 + t;
        int base = tid * 8;
        float4 f0 = *(const float4*)&hidden[base];
        float4 f1 = *(const float4*)&hidden[base + 4];
        s16x8 a;
        a[0] = (short)f2bf(f0.x); a[1] = (short)f2bf(f0.y);
        a[2] = (short)f2bf(f0.z); a[3] = (short)f2bf(f0.w);
        a[4] = (short)f2bf(f1.x); a[5] = (short)f2bf(f1.y);
        a[6] = (short)f2bf(f1.z); a[7] = (short)f2bf(f1.w);
        *(s16x8*)&hiddenBf[base] = a;
    }
}

// m97-class GEMM + 2-phase double-buffer (PROVEN round 9/10/14 template):
//   BN=128 (QKV): byte-identical to the round-9 proven path. 4 waves, wave 64x64.
//   BN=64  (proj): same sync/swizzle structure, wave 64x32 (acc[4][2]); B-tile
//     64x32 staged by 1 async16/wave; LDS 24KB. Fixes proj grid starvation:
//     grid 64x12 = 768 blocks = 3 blocks/CU (was 384 = 1.5/CU half-idle).
// Per K-step: stage(next->other buffer) BEFORE ds_read+MFMA(cur), ONE barrier.
// XCD slab swizzle (bijective for gridDim.x=64, any gridDim.y).
template <int OUT_F32, int BN>
__global__ __launch_bounds__(256) void gemm128(
    const unsigned short* __restrict__ A,
    const unsigned short* __restrict__ Bt,
    const float* __restrict__ bias,
    void* __restrict__ Cv,
    int M, int N, int K)
{
    constexpr int WN = (BN == 128) ? 64 : 32;   // wave output cols
    constexpr int NJ = WN / 16;                 // B fragments per wave
    __shared__ short As[2][128 * 32];
    __shared__ short Bs[2][BN * 32];
    int t = threadIdx.x, lane = t & 63, w = t >> 6;
    int quad = lane >> 4, low = lane & 15;
    // orig = (local<<3)|xcd ; (bx,by) = (xcd*8+(local&7), local>>3) — bijective.
    int orig = blockIdx.y * gridDim.x + blockIdx.x;
    int xcd = orig & 7;
    int local = orig >> 3;
    int bx = xcd * 8 + (local & 7);
    int by = local >> 3;
    int m0 = bx * 128, n0 = by * BN;
    int wm = (w & 1) * 64, wn = (w >> 1) * WN;

    // A staging (identical for both BN): chunks w*128+lane, +64
    int ci0 = w * 128 + lane;
    int r0 = ci0 >> 2, c0 = (ci0 & 3) ^ ((r0 >> 1) & 3);
    int ci1 = ci0 + 64;
    int r1 = ci1 >> 2, c1 = (ci1 & 3) ^ ((r1 >> 1) & 3);
    const unsigned short* pa0 = A + (long long)(m0 + r0) * K + c0 * 8;
    const unsigned short* pa1 = A + (long long)(m0 + r1) * K + c1 * 8;
    int alo0 = (w * 128) * 8;
    int alo1 = (w * 128 + 64) * 8;
    // B staging: BN=128 -> 2 chunks/thread (w*128+lane, +64); BN=64 -> 1 (w*64+lane)
    int cib0 = (BN == 128) ? (w * 128 + lane) : (w * 64 + lane);
    int rb0 = cib0 >> 2, cb0 = (cib0 & 3) ^ ((rb0 >> 1) & 3);
    const unsigned short* pb0 = Bt + (long long)(n0 + rb0) * K + cb0 * 8;
    int blo0 = (BN == 128) ? (w * 128) * 8 : (w * 64) * 8;
    int cib1 = cib0 + 64;
    int rb1 = cib1 >> 2, cb1 = (cib1 & 3) ^ ((rb1 >> 1) & 3);
    const unsigned short* pb1 = Bt + (long long)(n0 + rb1) * K + cb1 * 8;
    int blo1 = (w * 128 + 64) * 8;   // used only when BN==128

    // prologue: stage K-step 0 into buffer 0
    async16(&As[0][alo0], pa0);
    async16(&As[0][alo1], pa1);
    async16(&Bs[0][blo0], pb0);
    if (BN == 128) async16(&Bs[0][blo1], pb1);
    __syncthreads();

    f32x4 acc[4][NJ] = {};
    int cur = 0;
    for (int k0 = 0; k0 < K; k0 += 32) {
        int nxt = cur ^ 1;
        // stage next K-step into the other buffer (issued before compute;
        // lands by the barrier below, latency hidden under ds_read+MFMA)
        if (k0 + 32 < K) {
            async16(&As[nxt][alo0], pa0 + k0 + 32);
            async16(&As[nxt][alo1], pa1 + k0 + 32);
            async16(&Bs[nxt][blo0], pb0 + k0 + 32);
            if (BN == 128) async16(&Bs[nxt][blo1], pb1 + k0 + 32);
        }
        const short* as = As[cur];
        const short* bs = Bs[cur];
        s16x8 af[4], bfr[NJ];
        #pragma unroll
        for (int i = 0; i < 4; i++) {
            int ra = wm + i * 16 + low;
            af[i] = *(const s16x8*)&as[ra * 32 + ((quad ^ ((ra >> 1) & 3)) * 8)];
        }
        #pragma unroll
        for (int j = 0; j < NJ; j++) {
            int rbn = wn + j * 16 + low;
            bfr[j] = *(const s16x8*)&bs[rbn * 32 + ((quad ^ ((rbn >> 1) & 3)) * 8)];
        }
        #pragma unroll
        for (int i = 0; i < 4; i++)
            #pragma unroll
            for (int j = 0; j < NJ; j++)
                acc[i][j] = __builtin_amdgcn_mfma_f32_16x16x32_bf16(af[i], bfr[j], acc[i][j], 0, 0, 0);
        __syncthreads();   // reads of cur done (lgkm), stage of nxt landed (vmcnt)
        cur = nxt;
    }
    #pragma unroll
    for (int i = 0; i < 4; i++)
        #pragma unroll
        for (int j = 0; j < NJ; j++)
            #pragma unroll
            for (int r = 0; r < 4; r++) {
                int m = m0 + wm + i * 16 + quad * 4 + r;
                int n = n0 + wn + j * 16 + low;
                float v = acc[i][j][r] + bias[n];
                if (OUT_F32) ((float*)Cv)[(long long)m * N + n] = v;
                else ((unsigned short*)Cv)[(long long)m * N + n] = f2bf(v);
            }
}

// MFMA flash attention (round-10/14 PROVEN loop + symmetric epilogue v2):
// 2-gang KV split, 32 q-rows/wave, single-buffered staging, expf softmax,
// in-register P via swapped QK^T + v_cvt_pk_bf16_f32.
// Epilogue (r17): gang g finalizes q-half qh==g (ALL d-columns -> each wave
// still writes full 128B/row, same store shape as r14). Gang selection via a
// UNIFORM BRANCH copying o[0][*]/o[1][*] into named regs with COMPILE-TIME
// indices — r16's regression was runtime-indexed o[][] demoting the
// accumulator to scratch (WRITE_SIZE 405MB of spill traffic, rule #20).
// fp32 adds commute -> bit-identical output.
__global__ __launch_bounds__(512) void attn_k(
    const unsigned short* __restrict__ mixed,  // [8192][2304] : Q|K|V per row (bf16)
    unsigned short* __restrict__ ctx)          // [8192][768]
{
    // staging: per gang Ks 8192B + Vt 8704B = 16896B; 2 gangs 33792B.
    // epilogue overlay: xo 2048*f32x4 = 32768B + xl 512*f32 = 2048B -> 34816B.
    __shared__ __align__(16) char smem[34816];
    int blk = blockIdx.x;
    int bh = blk % 96;                 // XCD-grouped: 96 == 0 (mod 8)
    int qc = blk / 96;
    int b = bh / NHEAD, h = bh - b * NHEAD;
    int t = threadIdx.x;
    int tl = t & 255;                  // intra-gang thread id
    int lane = t & 63, w = t >> 6;     // w in 0..7
    int wq = w & 3, gang = w >> 2;
    int quad = lane >> 4, low = lane & 15;
    long long rowbase = (long long)b * SEQ;
    int q0 = qc * 128 + wq * 32;
    int hoff = h * HDIM;

    short* Ks = (short*)(smem + gang * 16896);        // K tile [kv][d], chunk-XOR swizzled
    short* Vt = (short*)(smem + gang * 16896 + 8192); // V^T tile [d][kv], kv padded ->68

    // Q fragments (B-operand of swapped QK^T; layout identical to A-frag): [qh][dhalf]
    s16x8 qf[2][2];
    #pragma unroll
    for (int qh = 0; qh < 2; qh++) {
        long long r = (rowbase + q0 + qh * 16 + low) * QKVN + hoff;
        qf[qh][0] = *(const s16x8*)&mixed[r + quad * 8];
        qf[qh][1] = *(const s16x8*)&mixed[r + 32 + quad * 8];
    }

    // K staging (per gang): slot = wq*128 + lane (+64); row = slot>>3, chunk = slot&7.
    // LDS phys chunk c of row r holds global d-chunk (c ^ (r&7)); read applies same XOR.
    int s0 = wq * 128 + lane;
    int kr0 = s0 >> 3, kc0 = s0 & 7;
    int kg = kc0 ^ (kr0 & 7);          // (kr0+8)&7 == kr0&7, so same for both slots
    const unsigned short* pk0 = mixed + (rowbase + kr0) * QKVN + EMBED + hoff + kg * 8;
    const unsigned short* pk1 = mixed + (rowbase + kr0 + 8) * QKVN + EMBED + hoff + kg * 8;
    short* lk0 = Ks + (wq * 128) * 8;
    short* lk1 = Ks + (wq * 128 + 64) * 8;

    // V staging (per gang): thread owns d = dblk*4..+3, kv rows rq*4..+3
    int dblk = tl & 15, rq = tl >> 4;
    const unsigned short* pv = mixed + (rowbase + rq * 4) * QKVN + 2 * EMBED + hoff + dblk * 4;

    f32x4 o[2][4] = {};
    float lsum[2] = {0.f, 0.f};

    int kvbase = gang * 512;           // gang's KV half
    for (int it = 0; it < 8; it++) {
        long long koff = (long long)(kvbase + it * 64) * QKVN;
        __syncthreads();
        async16(lk0, pk0 + koff);
        async16(lk1, pk1 + koff);
        s16x4 v0 = *(const s16x4*)&pv[koff];
        s16x4 v1 = *(const s16x4*)&pv[koff + QKVN];
        s16x4 v2 = *(const s16x4*)&pv[koff + 2 * QKVN];
        s16x4 v3 = *(const s16x4*)&pv[koff + 3 * QKVN];
        #pragma unroll
        for (int k = 0; k < 4; k++) {
            s16x4 wv;
            wv[0] = v0[k]; wv[1] = v1[k]; wv[2] = v2[k]; wv[3] = v3[k];
            *(s16x4*)&Vt[(dblk * 4 + k) * 68 + rq * 4] = wv;
        }
        __syncthreads();

        // S^T: per kv-16 block n, sT[qh][n][r] = S[q0+qh*16+low][kv...]
        f32x4 sT[2][4] = {};
        __builtin_amdgcn_s_setprio(1);
        #pragma unroll
        for (int n = 0; n < 4; n++) {
            int rr = n * 16 + low;
            int key = low & 7;
            s16x8 kf0 = *(const s16x8*)&Ks[rr * 64 + ((quad ^ key) * 8)];
            s16x8 kf1 = *(const s16x8*)&Ks[rr * 64 + (((quad + 4) ^ key) * 8)];
            sT[0][n] = __builtin_amdgcn_mfma_f32_16x16x32_bf16(kf0, qf[0][0], sT[0][n], 0, 0, 0);
            sT[0][n] = __builtin_amdgcn_mfma_f32_16x16x32_bf16(kf1, qf[0][1], sT[0][n], 0, 0, 0);
            sT[1][n] = __builtin_amdgcn_mfma_f32_16x16x32_bf16(kf0, qf[1][0], sT[1][n], 0, 0, 0);
            sT[1][n] = __builtin_amdgcn_mfma_f32_16x16x32_bf16(kf1, qf[1][1], sT[1][n], 0, 0, 0);
        }
        __builtin_amdgcn_s_setprio(0);

        // P = exp(S*scale): in-register, pack straight into x16 A-fragments
        s16x4 pf[2][4];
        #pragma unroll
        for (int qh = 0; qh < 2; qh++)
            #pragma unroll
            for (int n = 0; n < 4; n++) {
                float e0 = __expf(sT[qh][n][0] * ATTN_SCALE);
                float e1 = __expf(sT[qh][n][1] * ATTN_SCALE);
                float e2 = __expf(sT[qh][n][2] * ATTN_SCALE);
                float e3 = __expf(sT[qh][n][3] * ATTN_SCALE);
                lsum[qh] += (e0 + e1) + (e2 + e3);
                unsigned int w0, w1;
                asm("v_cvt_pk_bf16_f32 %0, %1, %2" : "=v"(w0) : "v"(e0), "v"(e1));
                asm("v_cvt_pk_bf16_f32 %0, %1, %2" : "=v"(w1) : "v"(e2), "v"(e3));
                union { unsigned int u[2]; s16x4 v; } pu;
                pu.u[0] = w0; pu.u[1] = w1;
                pf[qh][n] = pu.v;
            }

        // O += P @ V  (x16 MFMAs; V frag = contiguous b64 from V^T)
        __builtin_amdgcn_s_setprio(1);
        #pragma unroll
        for (int nt = 0; nt < 4; nt++) {
            int drow = nt * 16 + low;
            #pragma unroll
            for (int n = 0; n < 4; n++) {
                s16x4 vf = *(const s16x4*)&Vt[drow * 68 + n * 16 + quad * 4];
                o[0][nt] = mfma16(pf[0][n], vf, o[0][nt]);
                o[1][nt] = mfma16(pf[1][n], vf, o[1][nt]);
            }
        }
        __builtin_amdgcn_s_setprio(0);
    }

    // full row-sums within gang: combine the 4 quad-partials for each q=low
    #pragma unroll
    for (int qh = 0; qh < 2; qh++) {
        lsum[qh] += __shfl_xor(lsum[qh], 16, 64);
        lsum[qh] += __shfl_xor(lsum[qh], 32, 64);
    }

    // symmetric cross-gang combine by q-half (no-max softmax => pure addition).
    // Gang g finalizes qh==g. STATIC o-indexing via uniform branch (rule #20!).
    f32x4 od0, od1, od2, od3;   // dumped: this gang's o for the OTHER q-half
    f32x4 ok0, ok1, ok2, ok3;   // kept:   this gang's o for its own q-half
    float ld, lk;
    if (gang == 0) {
        od0 = o[1][0]; od1 = o[1][1]; od2 = o[1][2]; od3 = o[1][3];
        ok0 = o[0][0]; ok1 = o[0][1]; ok2 = o[0][2]; ok3 = o[0][3];
        ld = lsum[1]; lk = lsum[0];
    } else {
        od0 = o[0][0]; od1 = o[0][1]; od2 = o[0][2]; od3 = o[0][3];
        ok0 = o[1][0]; ok1 = o[1][1]; ok2 = o[1][2]; ok3 = o[1][3];
        ld = lsum[0]; lk = lsum[1];
    }
    f32x4* xo = (f32x4*)smem;                 // [src_gang][wq][nt][lane] = 2048 x f32x4
    float*  xl = (float*)(smem + 32768);      // [src_gang][wq][lane]    = 512 x f32
    int og = gang ^ 1;
    __syncthreads();                          // all staging reads done before overwrite
    {
        int base = (gang * 4 + wq) * 4;
        xo[(base + 0) * 64 + lane] = od0;
        xo[(base + 1) * 64 + lane] = od1;
        xo[(base + 2) * 64 + lane] = od2;
        xo[(base + 3) * 64 + lane] = od3;
        xl[(gang * 4 + wq) * 64 + lane] = ld;
    }
    __syncthreads();
    {
        int base = (og * 4 + wq) * 4;
        ok0 += xo[(base + 0) * 64 + lane];
        ok1 += xo[(base + 1) * 64 + lane];
        ok2 += xo[(base + 2) * 64 + lane];
        ok3 += xo[(base + 3) * 64 + lane];
        float lt = lk + xl[(og * 4 + wq) * 64 + lane];
        #pragma unroll
        for (int r = 0; r < 4; r++) {
            float inv = 1.0f / __shfl(lt, quad * 4 + r, 64);
            int q = q0 + gang * 16 + quad * 4 + r;
            long long rowoff = (rowbase + q) * EMBED + hoff;
            ctx[rowoff +  0 + low] = f2bf(ok0[r] * inv);
            ctx[rowoff + 16 + low] = f2bf(ok1[r] * inv);
            ctx[rowoff + 32 + low] = f2bf(ok2[r] * inv);
            ctx[rowoff + 48 + low] = f2bf(ok3[r] * inv);
        }
    }
}

extern "C" void kernel_launch(void* const* d_in, const int* in_sizes, int n_in,
                              void* d_out, int out_size, void* d_ws, size_t ws_size,
                              hipStream_t stream) {
    const float* hidden = (const float*)d_in[0];
    const float* qkv_w  = (const float*)d_in[1];
    const float* qkv_b  = (const float*)d_in[2];
    const float* proj_w = (const float*)d_in[3];
    const float* proj_b = (const float*)d_in[4];
    float* out = (float*)d_out;        // fp32 output

    char* ws = (char*)d_ws;
    // hiddenBf dead after QKV GEMM; ctx written only by attn -> alias (stream-serialized).
    unsigned short* hiddenBf = (unsigned short*)ws;                      // 8192x768  bf16
    unsigned short* ctx      = (unsigned short*)ws;                      // aliases hiddenBf
    unsigned short* WqkvT    = (unsigned short*)(ws + 12582912);         // 2304x768  bf16
    unsigned short* WprojT   = (unsigned short*)(ws + 16121856);         // 768x768   bf16
    unsigned short* mixed    = (unsigned short*)(ws + 17301504);         // 8192x2304 bf16

    prep_k<<<dim3(3648), 256, 0, stream>>>(qkv_w, WqkvT, proj_w, WprojT, hidden, hiddenBf);
    gemm128<0, 128><<<dim3(ROWS / 128, QKVN / 128), 256, 0, stream>>>(
        hiddenBf, WqkvT, qkv_b, mixed, ROWS, QKVN, EMBED);
    attn_k<<<dim3(96 * 8), 512, 0, stream>>>(mixed, ctx);
    gemm128<1, 64><<<dim3(ROWS / 128, EMBED / 64), 256, 0, stream>>>(
        ctx, WprojT, proj_b, out, ROWS, EMBED, EMBED);
}